// Round 5
// baseline (501.691 us; speedup 1.0000x reference)
//
#include <hip/hip_runtime.h>
#include <hip/hip_bf16.h>

#define D 64

typedef __attribute__((ext_vector_type(8))) short bf16x8;   // 8 bf16 in 4 VGPRs
typedef __attribute__((ext_vector_type(4))) float f32x4;

__device__ __forceinline__ short f2bf(float f) {
    __hip_bfloat16 h = __float2bfloat16(f);
    return *reinterpret_cast<short*>(&h);
}

// ---------------------------------------------------------------------------
// K1: per-node message MLP via MFMA.  m[v] = relu(x[v]@W1 + b1)@W2 + b2
// ---------------------------------------------------------------------------
__global__ __launch_bounds__(256) void msg_kernel(
    const float* __restrict__ x,
    const float* __restrict__ w1, const float* __restrict__ b1,
    const float* __restrict__ w2, const float* __restrict__ b2,
    float* __restrict__ m, int n_nodes)
{
    __shared__ __align__(16) __hip_bfloat16 sH[4][16 * 72];

    const int lane = threadIdx.x & 63;
    const int wslot = threadIdx.x >> 6;
    const int mr   = lane & 15;
    const int quad = lane >> 4;

    bf16x8 w1f[2][4], w2f[2][4];
    float  b1v[4], b2v[4];
#pragma unroll
    for (int ks = 0; ks < 2; ++ks)
#pragma unroll
        for (int nb = 0; nb < 4; ++nb) {
            bf16x8 f1, f2;
#pragma unroll
            for (int j = 0; j < 8; ++j) {
                int k = ks * 32 + quad * 8 + j;
                f1[j] = f2bf(w1[k * D + nb * 16 + mr]);
                f2[j] = f2bf(w2[k * D + nb * 16 + mr]);
            }
            w1f[ks][nb] = f1;
            w2f[ks][nb] = f2;
        }
#pragma unroll
    for (int nb = 0; nb < 4; ++nb) {
        b1v[nb] = b1[nb * 16 + mr];
        b2v[nb] = b2[nb * 16 + mr];
    }

    __hip_bfloat16* Hw = sH[wslot];
    const int wid    = (blockIdx.x * blockDim.x + threadIdx.x) >> 6;
    const int nwaves = (gridDim.x * blockDim.x) >> 6;
    const int ntiles = (n_nodes + 15) >> 4;

    for (int t = wid; t < ntiles; t += nwaves) {
        const int v0 = t * 16;
        int vr = v0 + mr;
        if (vr >= n_nodes) vr = n_nodes - 1;

        bf16x8 a[2];
#pragma unroll
        for (int ks = 0; ks < 2; ++ks) {
            const float* p = x + (size_t)vr * D + ks * 32 + quad * 8;
            float4 lo = *(const float4*)p;
            float4 hi = *(const float4*)(p + 4);
            bf16x8 f;
            f[0] = f2bf(lo.x); f[1] = f2bf(lo.y); f[2] = f2bf(lo.z); f[3] = f2bf(lo.w);
            f[4] = f2bf(hi.x); f[5] = f2bf(hi.y); f[6] = f2bf(hi.z); f[7] = f2bf(hi.w);
            a[ks] = f;
        }

#pragma unroll
        for (int nb = 0; nb < 4; ++nb) {
            f32x4 acc = {0.f, 0.f, 0.f, 0.f};
            acc = __builtin_amdgcn_mfma_f32_16x16x32_bf16(a[0], w1f[0][nb], acc, 0, 0, 0);
            acc = __builtin_amdgcn_mfma_f32_16x16x32_bf16(a[1], w1f[1][nb], acc, 0, 0, 0);
#pragma unroll
            for (int r = 0; r < 4; ++r) {
                float hv = fmaxf(acc[r] + b1v[nb], 0.f);
                Hw[(quad * 4 + r) * 72 + nb * 16 + mr] = __float2bfloat16(hv);
            }
        }

        bf16x8 h[2];
#pragma unroll
        for (int ks = 0; ks < 2; ++ks)
            h[ks] = *(const bf16x8*)&Hw[mr * 72 + ks * 32 + quad * 8];

#pragma unroll
        for (int nb = 0; nb < 4; ++nb) {
            f32x4 acc = {0.f, 0.f, 0.f, 0.f};
            acc = __builtin_amdgcn_mfma_f32_16x16x32_bf16(h[0], w2f[0][nb], acc, 0, 0, 0);
            acc = __builtin_amdgcn_mfma_f32_16x16x32_bf16(h[1], w2f[1][nb], acc, 0, 0, 0);
#pragma unroll
            for (int r = 0; r < 4; ++r) {
                int vrow = v0 + quad * 4 + r;
                if (vrow < n_nodes)
                    m[(size_t)vrow * D + nb * 16 + mr] = acc[r] + b2v[nb];
            }
        }
    }
}

// ---------------------------------------------------------------------------
// CSR build: histogram of destinations, exclusive scan, fill source list.
// Only ~2M scalar atomics total (vs 64M vector atomics in the old scatter).
// ---------------------------------------------------------------------------
__global__ __launch_bounds__(256) void hist_kernel(
    const int* __restrict__ col, int* __restrict__ deg, int n_edges)
{
    int e = blockIdx.x * blockDim.x + threadIdx.x;
    if (e < n_edges) atomicAdd(&deg[col[e]], 1);
}

// Single-block exclusive scan of deg[0..n) -> offs, cursor (1024 threads).
__global__ __launch_bounds__(1024) void scan_kernel(
    const int* __restrict__ deg, int* __restrict__ offs,
    int* __restrict__ cursor, int n)
{
    __shared__ int part[1024];
    const int t = threadIdx.x;
    const int chunk = (n + 1023) >> 10;
    const int beg = t * chunk;
    const int fin = min(beg + chunk, n);

    int s = 0;
    for (int i = beg; i < fin; ++i) s += deg[i];
    part[t] = s;
    __syncthreads();

    // Hillis-Steele inclusive scan over 1024 partials
    for (int off = 1; off < 1024; off <<= 1) {
        int v = (t >= off) ? part[t - off] : 0;
        __syncthreads();
        part[t] += v;
        __syncthreads();
    }

    int run = (t == 0) ? 0 : part[t - 1];
    for (int i = beg; i < fin; ++i) {
        offs[i]   = run;
        cursor[i] = run;
        run += deg[i];
    }
}

// srcs[pos] = row[e] for each edge, bucketed by destination col[e].
__global__ __launch_bounds__(256) void fill_kernel(
    const int* __restrict__ row, const int* __restrict__ col,
    int* __restrict__ cursor, int* __restrict__ srcs, int n_edges)
{
    int e = blockIdx.x * blockDim.x + threadIdx.x;
    if (e < n_edges) {
        int c = col[e];
        int pos = atomicAdd(&cursor[c], 1);
        srcs[pos] = row[e];
    }
}

// ---------------------------------------------------------------------------
// K2: atomic-free gather.  agg[v] = sum over incoming edges of m[src].
// One wave per node; lane = feature. Source ids loaded coalesced into lanes,
// broadcast via readlane, 4 m-rows in flight for ILP.
// ---------------------------------------------------------------------------
__global__ __launch_bounds__(256) void gather_kernel(
    const int* __restrict__ offs, const int* __restrict__ cursor,
    const int* __restrict__ srcs, const float* __restrict__ m,
    float* __restrict__ agg, int n_nodes)
{
    const int lane = threadIdx.x & 63;
    const int v    = (blockIdx.x * blockDim.x + threadIdx.x) >> 6;
    if (v >= n_nodes) return;

    const int start = offs[v];
    const int end   = cursor[v];   // cursor[v] == offs[v] + deg[v] after fill

    float s = 0.0f;
    for (int cs = start; cs < end; cs += 64) {
        const int cnt = min(64, end - cs);
        int rl = 0;
        if (lane < cnt) rl = srcs[cs + lane];

        int j = 0;
        for (; j + 4 <= cnt; j += 4) {
            int r0 = __builtin_amdgcn_readlane(rl, j + 0);
            int r1 = __builtin_amdgcn_readlane(rl, j + 1);
            int r2 = __builtin_amdgcn_readlane(rl, j + 2);
            int r3 = __builtin_amdgcn_readlane(rl, j + 3);
            float v0 = m[(size_t)r0 * D + lane];
            float v1 = m[(size_t)r1 * D + lane];
            float v2 = m[(size_t)r2 * D + lane];
            float v3 = m[(size_t)r3 * D + lane];
            s += v0; s += v1; s += v2; s += v3;
        }
        for (; j < cnt; ++j) {
            int r = __builtin_amdgcn_readlane(rl, j);
            s += m[(size_t)r * D + lane];
        }
    }
    agg[(size_t)v * D + lane] = s;
}

// ---------------------------------------------------------------------------
// Fallback scatter (used only if ws is too small for CSR): fp32 atomics.
// ---------------------------------------------------------------------------
__global__ __launch_bounds__(256) void scatter_kernel(
    const int* __restrict__ row, const int* __restrict__ col,
    const float* __restrict__ m, float* __restrict__ agg, int n_edges)
{
    const int lane = threadIdx.x & 63;
    const int wid  = (blockIdx.x * blockDim.x + threadIdx.x) >> 6;
    const int base = wid * 64;
    if (base >= n_edges) return;
    const int cnt = min(64, n_edges - base);

    int my_r = 0, my_c = 0;
    if (lane < cnt) { my_r = row[base + lane]; my_c = col[base + lane]; }

    for (int j = 0; j < cnt; ++j) {
        int r = __builtin_amdgcn_readlane(my_r, j);
        int c = __builtin_amdgcn_readlane(my_c, j);
        float v = m[(size_t)r * D + lane];
        atomicAdd(&agg[(size_t)c * D + lane], v);
    }
}

// ---------------------------------------------------------------------------
// K3: output MLP via MFMA.  out[v] = relu([x[v],agg[v]]@OW1 + ob1)@OW2 + ob2
// ---------------------------------------------------------------------------
__global__ __launch_bounds__(256) void out_kernel(
    const float* __restrict__ x, const float* __restrict__ agg,
    const float* __restrict__ w1, const float* __restrict__ b1,
    const float* __restrict__ w2, const float* __restrict__ b2,
    float* __restrict__ out, int n_nodes)
{
    __shared__ __align__(16) __hip_bfloat16 sH[4][16 * 72];

    const int lane = threadIdx.x & 63;
    const int wslot = threadIdx.x >> 6;
    const int mr   = lane & 15;
    const int quad = lane >> 4;

    bf16x8 w1f[4][4], w2f[2][4];
    float  b1v[4], b2v[4];
#pragma unroll
    for (int ks = 0; ks < 4; ++ks)
#pragma unroll
        for (int nb = 0; nb < 4; ++nb) {
            bf16x8 f;
#pragma unroll
            for (int j = 0; j < 8; ++j) {
                int k = ks * 32 + quad * 8 + j;
                f[j] = f2bf(w1[k * D + nb * 16 + mr]);
            }
            w1f[ks][nb] = f;
        }
#pragma unroll
    for (int ks = 0; ks < 2; ++ks)
#pragma unroll
        for (int nb = 0; nb < 4; ++nb) {
            bf16x8 f;
#pragma unroll
            for (int j = 0; j < 8; ++j) {
                int k = ks * 32 + quad * 8 + j;
                f[j] = f2bf(w2[k * D + nb * 16 + mr]);
            }
            w2f[ks][nb] = f;
        }
#pragma unroll
    for (int nb = 0; nb < 4; ++nb) {
        b1v[nb] = b1[nb * 16 + mr];
        b2v[nb] = b2[nb * 16 + mr];
    }

    __hip_bfloat16* Hw = sH[wslot];
    const int wid    = (blockIdx.x * blockDim.x + threadIdx.x) >> 6;
    const int nwaves = (gridDim.x * blockDim.x) >> 6;
    const int ntiles = (n_nodes + 15) >> 4;

    for (int t = wid; t < ntiles; t += nwaves) {
        const int v0 = t * 16;
        int vr = v0 + mr;
        if (vr >= n_nodes) vr = n_nodes - 1;

        bf16x8 a[4];
#pragma unroll
        for (int ks = 0; ks < 4; ++ks) {
            const float* src = (ks < 2) ? (x + (size_t)vr * D + ks * 32)
                                        : (agg + (size_t)vr * D + (ks - 2) * 32);
            const float* p = src + quad * 8;
            float4 lo = *(const float4*)p;
            float4 hi = *(const float4*)(p + 4);
            bf16x8 f;
            f[0] = f2bf(lo.x); f[1] = f2bf(lo.y); f[2] = f2bf(lo.z); f[3] = f2bf(lo.w);
            f[4] = f2bf(hi.x); f[5] = f2bf(hi.y); f[6] = f2bf(hi.z); f[7] = f2bf(hi.w);
            a[ks] = f;
        }

#pragma unroll
        for (int nb = 0; nb < 4; ++nb) {
            f32x4 acc = {0.f, 0.f, 0.f, 0.f};
#pragma unroll
            for (int ks = 0; ks < 4; ++ks)
                acc = __builtin_amdgcn_mfma_f32_16x16x32_bf16(a[ks], w1f[ks][nb], acc, 0, 0, 0);
#pragma unroll
            for (int r = 0; r < 4; ++r) {
                float hv = fmaxf(acc[r] + b1v[nb], 0.f);
                Hw[(quad * 4 + r) * 72 + nb * 16 + mr] = __float2bfloat16(hv);
            }
        }

        bf16x8 h[2];
#pragma unroll
        for (int ks = 0; ks < 2; ++ks)
            h[ks] = *(const bf16x8*)&Hw[mr * 72 + ks * 32 + quad * 8];

#pragma unroll
        for (int nb = 0; nb < 4; ++nb) {
            f32x4 acc = {0.f, 0.f, 0.f, 0.f};
            acc = __builtin_amdgcn_mfma_f32_16x16x32_bf16(h[0], w2f[0][nb], acc, 0, 0, 0);
            acc = __builtin_amdgcn_mfma_f32_16x16x32_bf16(h[1], w2f[1][nb], acc, 0, 0, 0);
#pragma unroll
            for (int r = 0; r < 4; ++r) {
                int vrow = v0 + quad * 4 + r;
                if (vrow < n_nodes)
                    out[(size_t)vrow * D + nb * 16 + mr] = acc[r] + b2v[nb];
            }
        }
    }
}

// ---------------------------------------------------------------------------
extern "C" void kernel_launch(void* const* d_in, const int* in_sizes, int n_in,
                              void* d_out, int out_size, void* d_ws, size_t ws_size,
                              hipStream_t stream) {
    const float* x   = (const float*)d_in[0];
    const int*   ei  = (const int*)d_in[1];
    // d_in[2] = batch (unused)
    const float* mw1 = (const float*)d_in[3];
    const float* mb1 = (const float*)d_in[4];
    const float* mw2 = (const float*)d_in[5];
    const float* mb2 = (const float*)d_in[6];
    const float* ow1 = (const float*)d_in[7];
    const float* ob1 = (const float*)d_in[8];
    const float* ow2 = (const float*)d_in[9];
    const float* ob2 = (const float*)d_in[10];

    const int n_nodes = in_sizes[0] / D;        // 100000
    const int n_edges = in_sizes[1] / 2;        // 1000000
    const int* row = ei;                        // edge_index[0]
    const int* col = ei + n_edges;              // edge_index[1]

    // ws layout
    float* m   = (float*)d_ws;                       // [n_nodes*64] f32
    float* agg = m + (size_t)n_nodes * D;            // [n_nodes*64] f32
    int* deg    = (int*)(agg + (size_t)n_nodes * D); // [n_nodes]
    int* offs   = deg + n_nodes;                     // [n_nodes]
    int* cursor = offs + n_nodes;                    // [n_nodes]
    int* srcs   = cursor + n_nodes;                  // [n_edges]
    const size_t need_csr = (size_t)n_nodes * D * 8 + (size_t)n_nodes * 12
                          + (size_t)n_edges * 4;

    const int ntiles = (n_nodes + 15) / 16;
    const int nblk   = (ntiles + 3) / 4;

    msg_kernel<<<nblk, 256, 0, stream>>>(x, mw1, mb1, mw2, mb2, m, n_nodes);

    if (ws_size >= need_csr) {
        // CSR build + atomic-free gather
        hipMemsetAsync(deg, 0, (size_t)n_nodes * sizeof(int), stream);
        hist_kernel<<<(n_edges + 255) / 256, 256, 0, stream>>>(col, deg, n_edges);
        scan_kernel<<<1, 1024, 0, stream>>>(deg, offs, cursor, n_nodes);
        fill_kernel<<<(n_edges + 255) / 256, 256, 0, stream>>>(row, col, cursor, srcs, n_edges);
        gather_kernel<<<(n_nodes + 3) / 4, 256, 0, stream>>>(offs, cursor, srcs, m, agg, n_nodes);
    } else {
        // Fallback: atomic scatter
        hipMemsetAsync(agg, 0, (size_t)n_nodes * D * sizeof(float), stream);
        const int nwaves_s = (n_edges + 63) / 64;
        scatter_kernel<<<(nwaves_s + 3) / 4, 256, 0, stream>>>(row, col, m, agg, n_edges);
    }

    out_kernel<<<nblk, 256, 0, stream>>>(x, agg, ow1, ob1, ow2, ob2,
                                         (float*)d_out, n_nodes);
}

// Round 6
// 285.443 us; speedup vs baseline: 1.7576x; 1.7576x over previous
//
#include <hip/hip_runtime.h>
#include <hip/hip_bf16.h>

#define D 64

typedef __attribute__((ext_vector_type(8))) short bf16x8;   // 8 bf16 in 4 VGPRs
typedef __attribute__((ext_vector_type(4))) float f32x4;

__device__ __forceinline__ short f2bf(float f) {
    __hip_bfloat16 h = __float2bfloat16(f);
    return *reinterpret_cast<short*>(&h);
}

// ---------------------------------------------------------------------------
// K1: per-node message MLP via MFMA.  m[v] = relu(x[v]@W1 + b1)@W2 + b2
// ---------------------------------------------------------------------------
__global__ __launch_bounds__(256) void msg_kernel(
    const float* __restrict__ x,
    const float* __restrict__ w1, const float* __restrict__ b1,
    const float* __restrict__ w2, const float* __restrict__ b2,
    float* __restrict__ m, int n_nodes)
{
    __shared__ __align__(16) __hip_bfloat16 sH[4][16 * 72];

    const int lane = threadIdx.x & 63;
    const int wslot = threadIdx.x >> 6;
    const int mr   = lane & 15;
    const int quad = lane >> 4;

    bf16x8 w1f[2][4], w2f[2][4];
    float  b1v[4], b2v[4];
#pragma unroll
    for (int ks = 0; ks < 2; ++ks)
#pragma unroll
        for (int nb = 0; nb < 4; ++nb) {
            bf16x8 f1, f2;
#pragma unroll
            for (int j = 0; j < 8; ++j) {
                int k = ks * 32 + quad * 8 + j;
                f1[j] = f2bf(w1[k * D + nb * 16 + mr]);
                f2[j] = f2bf(w2[k * D + nb * 16 + mr]);
            }
            w1f[ks][nb] = f1;
            w2f[ks][nb] = f2;
        }
#pragma unroll
    for (int nb = 0; nb < 4; ++nb) {
        b1v[nb] = b1[nb * 16 + mr];
        b2v[nb] = b2[nb * 16 + mr];
    }

    __hip_bfloat16* Hw = sH[wslot];
    const int wid    = (blockIdx.x * blockDim.x + threadIdx.x) >> 6;
    const int nwaves = (gridDim.x * blockDim.x) >> 6;
    const int ntiles = (n_nodes + 15) >> 4;

    for (int t = wid; t < ntiles; t += nwaves) {
        const int v0 = t * 16;
        int vr = v0 + mr;
        if (vr >= n_nodes) vr = n_nodes - 1;

        bf16x8 a[2];
#pragma unroll
        for (int ks = 0; ks < 2; ++ks) {
            const float* p = x + (size_t)vr * D + ks * 32 + quad * 8;
            float4 lo = *(const float4*)p;
            float4 hi = *(const float4*)(p + 4);
            bf16x8 f;
            f[0] = f2bf(lo.x); f[1] = f2bf(lo.y); f[2] = f2bf(lo.z); f[3] = f2bf(lo.w);
            f[4] = f2bf(hi.x); f[5] = f2bf(hi.y); f[6] = f2bf(hi.z); f[7] = f2bf(hi.w);
            a[ks] = f;
        }

#pragma unroll
        for (int nb = 0; nb < 4; ++nb) {
            f32x4 acc = {0.f, 0.f, 0.f, 0.f};
            acc = __builtin_amdgcn_mfma_f32_16x16x32_bf16(a[0], w1f[0][nb], acc, 0, 0, 0);
            acc = __builtin_amdgcn_mfma_f32_16x16x32_bf16(a[1], w1f[1][nb], acc, 0, 0, 0);
#pragma unroll
            for (int r = 0; r < 4; ++r) {
                float hv = fmaxf(acc[r] + b1v[nb], 0.f);
                Hw[(quad * 4 + r) * 72 + nb * 16 + mr] = __float2bfloat16(hv);
            }
        }

        bf16x8 h[2];
#pragma unroll
        for (int ks = 0; ks < 2; ++ks)
            h[ks] = *(const bf16x8*)&Hw[mr * 72 + ks * 32 + quad * 8];

#pragma unroll
        for (int nb = 0; nb < 4; ++nb) {
            f32x4 acc = {0.f, 0.f, 0.f, 0.f};
            acc = __builtin_amdgcn_mfma_f32_16x16x32_bf16(h[0], w2f[0][nb], acc, 0, 0, 0);
            acc = __builtin_amdgcn_mfma_f32_16x16x32_bf16(h[1], w2f[1][nb], acc, 0, 0, 0);
#pragma unroll
            for (int r = 0; r < 4; ++r) {
                int vrow = v0 + quad * 4 + r;
                if (vrow < n_nodes)
                    m[(size_t)vrow * D + nb * 16 + mr] = acc[r] + b2v[nb];
            }
        }
    }
}

// ---------------------------------------------------------------------------
// CSR build: histogram, 3-phase parallel exclusive scan, fill.
// ---------------------------------------------------------------------------
__global__ __launch_bounds__(256) void hist_kernel(
    const int* __restrict__ col, int* __restrict__ deg, int n_edges)
{
    int e = blockIdx.x * blockDim.x + threadIdx.x;
    if (e < n_edges) atomicAdd(&deg[col[e]], 1);
}

// Phase A: per-block (256-wide tile) sums, coalesced.
__global__ __launch_bounds__(256) void scan_partial_kernel(
    const int* __restrict__ deg, int* __restrict__ bsum, int n)
{
    __shared__ int ws[4];
    const int g = blockIdx.x * 256 + threadIdx.x;
    int v = (g < n) ? deg[g] : 0;
#pragma unroll
    for (int off = 32; off > 0; off >>= 1)
        v += __shfl_down(v, off, 64);
    if ((threadIdx.x & 63) == 0) ws[threadIdx.x >> 6] = v;
    __syncthreads();
    if (threadIdx.x == 0)
        bsum[blockIdx.x] = ws[0] + ws[1] + ws[2] + ws[3];
}

// Phase B: single small block scans the partials (exclusive), nparts <= 512.
__global__ __launch_bounds__(512) void scan_tops_kernel(
    const int* __restrict__ bsum, int* __restrict__ bscan, int nparts)
{
    __shared__ int tmp[512];
    const int t = threadIdx.x;
    int v = (t < nparts) ? bsum[t] : 0;
    tmp[t] = v;
    __syncthreads();
    for (int off = 1; off < 512; off <<= 1) {
        int u = (t >= off) ? tmp[t - off] : 0;
        __syncthreads();
        tmp[t] += u;
        __syncthreads();
    }
    if (t < nparts) bscan[t] = tmp[t] - v;   // exclusive
}

// Phase C: per-block LDS exclusive scan + base, coalesced writes.
__global__ __launch_bounds__(256) void scan_apply_kernel(
    const int* __restrict__ deg, const int* __restrict__ bscan,
    int* __restrict__ offs, int* __restrict__ cursor, int n)
{
    __shared__ int tmp[256];
    const int t = threadIdx.x;
    const int g = blockIdx.x * 256 + t;
    int v = (g < n) ? deg[g] : 0;
    tmp[t] = v;
    __syncthreads();
    for (int off = 1; off < 256; off <<= 1) {
        int u = (t >= off) ? tmp[t - off] : 0;
        __syncthreads();
        tmp[t] += u;
        __syncthreads();
    }
    if (g < n) {
        int e = bscan[blockIdx.x] + tmp[t] - v;  // exclusive prefix
        offs[g]   = e;
        cursor[g] = e;
    }
}

// srcs[pos] = row[e] for each edge, bucketed by destination col[e].
__global__ __launch_bounds__(256) void fill_kernel(
    const int* __restrict__ row, const int* __restrict__ col,
    int* __restrict__ cursor, int* __restrict__ srcs, int n_edges)
{
    int e = blockIdx.x * blockDim.x + threadIdx.x;
    if (e < n_edges) {
        int c = col[e];
        int pos = atomicAdd(&cursor[c], 1);
        srcs[pos] = row[e];
    }
}

// ---------------------------------------------------------------------------
// K2: atomic-free gather.  agg[v] = sum over incoming edges of m[src].
// ---------------------------------------------------------------------------
__global__ __launch_bounds__(256) void gather_kernel(
    const int* __restrict__ offs, const int* __restrict__ cursor,
    const int* __restrict__ srcs, const float* __restrict__ m,
    float* __restrict__ agg, int n_nodes)
{
    const int lane = threadIdx.x & 63;
    const int v    = (blockIdx.x * blockDim.x + threadIdx.x) >> 6;
    if (v >= n_nodes) return;

    const int start = offs[v];
    const int end   = cursor[v];   // cursor[v] == offs[v] + deg[v] after fill

    float s = 0.0f;
    for (int cs = start; cs < end; cs += 64) {
        const int cnt = min(64, end - cs);
        int rl = 0;
        if (lane < cnt) rl = srcs[cs + lane];

        int j = 0;
        for (; j + 4 <= cnt; j += 4) {
            int r0 = __builtin_amdgcn_readlane(rl, j + 0);
            int r1 = __builtin_amdgcn_readlane(rl, j + 1);
            int r2 = __builtin_amdgcn_readlane(rl, j + 2);
            int r3 = __builtin_amdgcn_readlane(rl, j + 3);
            float v0 = m[(size_t)r0 * D + lane];
            float v1 = m[(size_t)r1 * D + lane];
            float v2 = m[(size_t)r2 * D + lane];
            float v3 = m[(size_t)r3 * D + lane];
            s += v0; s += v1; s += v2; s += v3;
        }
        for (; j < cnt; ++j) {
            int r = __builtin_amdgcn_readlane(rl, j);
            s += m[(size_t)r * D + lane];
        }
    }
    agg[(size_t)v * D + lane] = s;
}

// ---------------------------------------------------------------------------
// Fallback scatter (only if ws too small for CSR): fp32 atomics.
// ---------------------------------------------------------------------------
__global__ __launch_bounds__(256) void scatter_kernel(
    const int* __restrict__ row, const int* __restrict__ col,
    const float* __restrict__ m, float* __restrict__ agg, int n_edges)
{
    const int lane = threadIdx.x & 63;
    const int wid  = (blockIdx.x * blockDim.x + threadIdx.x) >> 6;
    const int base = wid * 64;
    if (base >= n_edges) return;
    const int cnt = min(64, n_edges - base);

    int my_r = 0, my_c = 0;
    if (lane < cnt) { my_r = row[base + lane]; my_c = col[base + lane]; }

    for (int j = 0; j < cnt; ++j) {
        int r = __builtin_amdgcn_readlane(my_r, j);
        int c = __builtin_amdgcn_readlane(my_c, j);
        float v = m[(size_t)r * D + lane];
        atomicAdd(&agg[(size_t)c * D + lane], v);
    }
}

// ---------------------------------------------------------------------------
// K3: output MLP via MFMA.  out[v] = relu([x[v],agg[v]]@OW1 + ob1)@OW2 + ob2
// ---------------------------------------------------------------------------
__global__ __launch_bounds__(256) void out_kernel(
    const float* __restrict__ x, const float* __restrict__ agg,
    const float* __restrict__ w1, const float* __restrict__ b1,
    const float* __restrict__ w2, const float* __restrict__ b2,
    float* __restrict__ out, int n_nodes)
{
    __shared__ __align__(16) __hip_bfloat16 sH[4][16 * 72];

    const int lane = threadIdx.x & 63;
    const int wslot = threadIdx.x >> 6;
    const int mr   = lane & 15;
    const int quad = lane >> 4;

    bf16x8 w1f[4][4], w2f[2][4];
    float  b1v[4], b2v[4];
#pragma unroll
    for (int ks = 0; ks < 4; ++ks)
#pragma unroll
        for (int nb = 0; nb < 4; ++nb) {
            bf16x8 f;
#pragma unroll
            for (int j = 0; j < 8; ++j) {
                int k = ks * 32 + quad * 8 + j;
                f[j] = f2bf(w1[k * D + nb * 16 + mr]);
            }
            w1f[ks][nb] = f;
        }
#pragma unroll
    for (int ks = 0; ks < 2; ++ks)
#pragma unroll
        for (int nb = 0; nb < 4; ++nb) {
            bf16x8 f;
#pragma unroll
            for (int j = 0; j < 8; ++j) {
                int k = ks * 32 + quad * 8 + j;
                f[j] = f2bf(w2[k * D + nb * 16 + mr]);
            }
            w2f[ks][nb] = f;
        }
#pragma unroll
    for (int nb = 0; nb < 4; ++nb) {
        b1v[nb] = b1[nb * 16 + mr];
        b2v[nb] = b2[nb * 16 + mr];
    }

    __hip_bfloat16* Hw = sH[wslot];
    const int wid    = (blockIdx.x * blockDim.x + threadIdx.x) >> 6;
    const int nwaves = (gridDim.x * blockDim.x) >> 6;
    const int ntiles = (n_nodes + 15) >> 4;

    for (int t = wid; t < ntiles; t += nwaves) {
        const int v0 = t * 16;
        int vr = v0 + mr;
        if (vr >= n_nodes) vr = n_nodes - 1;

        bf16x8 a[4];
#pragma unroll
        for (int ks = 0; ks < 4; ++ks) {
            const float* src = (ks < 2) ? (x + (size_t)vr * D + ks * 32)
                                        : (agg + (size_t)vr * D + (ks - 2) * 32);
            const float* p = src + quad * 8;
            float4 lo = *(const float4*)p;
            float4 hi = *(const float4*)(p + 4);
            bf16x8 f;
            f[0] = f2bf(lo.x); f[1] = f2bf(lo.y); f[2] = f2bf(lo.z); f[3] = f2bf(lo.w);
            f[4] = f2bf(hi.x); f[5] = f2bf(hi.y); f[6] = f2bf(hi.z); f[7] = f2bf(hi.w);
            a[ks] = f;
        }

#pragma unroll
        for (int nb = 0; nb < 4; ++nb) {
            f32x4 acc = {0.f, 0.f, 0.f, 0.f};
#pragma unroll
            for (int ks = 0; ks < 4; ++ks)
                acc = __builtin_amdgcn_mfma_f32_16x16x32_bf16(a[ks], w1f[ks][nb], acc, 0, 0, 0);
#pragma unroll
            for (int r = 0; r < 4; ++r) {
                float hv = fmaxf(acc[r] + b1v[nb], 0.f);
                Hw[(quad * 4 + r) * 72 + nb * 16 + mr] = __float2bfloat16(hv);
            }
        }

        bf16x8 h[2];
#pragma unroll
        for (int ks = 0; ks < 2; ++ks)
            h[ks] = *(const bf16x8*)&Hw[mr * 72 + ks * 32 + quad * 8];

#pragma unroll
        for (int nb = 0; nb < 4; ++nb) {
            f32x4 acc = {0.f, 0.f, 0.f, 0.f};
            acc = __builtin_amdgcn_mfma_f32_16x16x32_bf16(h[0], w2f[0][nb], acc, 0, 0, 0);
            acc = __builtin_amdgcn_mfma_f32_16x16x32_bf16(h[1], w2f[1][nb], acc, 0, 0, 0);
#pragma unroll
            for (int r = 0; r < 4; ++r) {
                int vrow = v0 + quad * 4 + r;
                if (vrow < n_nodes)
                    out[(size_t)vrow * D + nb * 16 + mr] = acc[r] + b2v[nb];
            }
        }
    }
}

// ---------------------------------------------------------------------------
extern "C" void kernel_launch(void* const* d_in, const int* in_sizes, int n_in,
                              void* d_out, int out_size, void* d_ws, size_t ws_size,
                              hipStream_t stream) {
    const float* x   = (const float*)d_in[0];
    const int*   ei  = (const int*)d_in[1];
    // d_in[2] = batch (unused)
    const float* mw1 = (const float*)d_in[3];
    const float* mb1 = (const float*)d_in[4];
    const float* mw2 = (const float*)d_in[5];
    const float* mb2 = (const float*)d_in[6];
    const float* ow1 = (const float*)d_in[7];
    const float* ob1 = (const float*)d_in[8];
    const float* ow2 = (const float*)d_in[9];
    const float* ob2 = (const float*)d_in[10];

    const int n_nodes = in_sizes[0] / D;        // 100000
    const int n_edges = in_sizes[1] / 2;        // 1000000
    const int* row = ei;                        // edge_index[0]
    const int* col = ei + n_edges;              // edge_index[1]

    const int nparts = (n_nodes + 255) / 256;   // 391 (must be <= 512)

    // ws layout
    float* m   = (float*)d_ws;                       // [n_nodes*64] f32
    float* agg = m + (size_t)n_nodes * D;            // [n_nodes*64] f32
    int* deg    = (int*)(agg + (size_t)n_nodes * D); // [n_nodes]
    int* offs   = deg + n_nodes;                     // [n_nodes]
    int* cursor = offs + n_nodes;                    // [n_nodes]
    int* srcs   = cursor + n_nodes;                  // [n_edges]
    int* bsum   = srcs + n_edges;                    // [nparts]
    int* bscan  = bsum + nparts;                     // [nparts]
    const size_t need_csr = (size_t)n_nodes * D * 8 + (size_t)n_nodes * 12
                          + (size_t)n_edges * 4 + (size_t)nparts * 8;

    const int ntiles = (n_nodes + 15) / 16;
    const int nblk   = (ntiles + 3) / 4;

    msg_kernel<<<nblk, 256, 0, stream>>>(x, mw1, mb1, mw2, mb2, m, n_nodes);

    if (ws_size >= need_csr && nparts <= 512) {
        hipMemsetAsync(deg, 0, (size_t)n_nodes * sizeof(int), stream);
        hist_kernel<<<(n_edges + 255) / 256, 256, 0, stream>>>(col, deg, n_edges);
        scan_partial_kernel<<<nparts, 256, 0, stream>>>(deg, bsum, n_nodes);
        scan_tops_kernel<<<1, 512, 0, stream>>>(bsum, bscan, nparts);
        scan_apply_kernel<<<nparts, 256, 0, stream>>>(deg, bscan, offs, cursor, n_nodes);
        fill_kernel<<<(n_edges + 255) / 256, 256, 0, stream>>>(row, col, cursor, srcs, n_edges);
        gather_kernel<<<(n_nodes + 3) / 4, 256, 0, stream>>>(offs, cursor, srcs, m, agg, n_nodes);
    } else {
        hipMemsetAsync(agg, 0, (size_t)n_nodes * D * sizeof(float), stream);
        const int nwaves_s = (n_edges + 63) / 64;
        scatter_kernel<<<(nwaves_s + 3) / 4, 256, 0, stream>>>(row, col, m, agg, n_edges);
    }

    out_kernel<<<nblk, 256, 0, stream>>>(x, agg, ow1, ob1, ow2, ob2,
                                         (float*)d_out, n_nodes);
}

// Round 7
// 279.906 us; speedup vs baseline: 1.7924x; 1.0198x over previous
//
#include <hip/hip_runtime.h>
#include <hip/hip_bf16.h>

#define D 64
#define BSHIFT 11
#define BW (1 << BSHIFT)          // bucket width: 2048 destination nodes
#define MAXK 64                   // max buckets (n_nodes <= 131072 for 17-bit pack)

typedef __attribute__((ext_vector_type(8))) short bf16x8;   // 8 bf16 in 4 VGPRs
typedef __attribute__((ext_vector_type(4))) float f32x4;

__device__ __forceinline__ short f2bf(float f) {
    __hip_bfloat16 h = __float2bfloat16(f);
    return *reinterpret_cast<short*>(&h);
}

// ---------------------------------------------------------------------------
// K1: per-node message MLP via MFMA.  m[v] = relu(x[v]@W1 + b1)@W2 + b2
// ---------------------------------------------------------------------------
__global__ __launch_bounds__(256) void msg_kernel(
    const float* __restrict__ x,
    const float* __restrict__ w1, const float* __restrict__ b1,
    const float* __restrict__ w2, const float* __restrict__ b2,
    float* __restrict__ m, int n_nodes)
{
    __shared__ __align__(16) __hip_bfloat16 sH[4][16 * 72];

    const int lane = threadIdx.x & 63;
    const int wslot = threadIdx.x >> 6;
    const int mr   = lane & 15;
    const int quad = lane >> 4;

    bf16x8 w1f[2][4], w2f[2][4];
    float  b1v[4], b2v[4];
#pragma unroll
    for (int ks = 0; ks < 2; ++ks)
#pragma unroll
        for (int nb = 0; nb < 4; ++nb) {
            bf16x8 f1, f2;
#pragma unroll
            for (int j = 0; j < 8; ++j) {
                int k = ks * 32 + quad * 8 + j;
                f1[j] = f2bf(w1[k * D + nb * 16 + mr]);
                f2[j] = f2bf(w2[k * D + nb * 16 + mr]);
            }
            w1f[ks][nb] = f1;
            w2f[ks][nb] = f2;
        }
#pragma unroll
    for (int nb = 0; nb < 4; ++nb) {
        b1v[nb] = b1[nb * 16 + mr];
        b2v[nb] = b2[nb * 16 + mr];
    }

    __hip_bfloat16* Hw = sH[wslot];
    const int wid    = (blockIdx.x * blockDim.x + threadIdx.x) >> 6;
    const int nwaves = (gridDim.x * blockDim.x) >> 6;
    const int ntiles = (n_nodes + 15) >> 4;

    for (int t = wid; t < ntiles; t += nwaves) {
        const int v0 = t * 16;
        int vr = v0 + mr;
        if (vr >= n_nodes) vr = n_nodes - 1;

        bf16x8 a[2];
#pragma unroll
        for (int ks = 0; ks < 2; ++ks) {
            const float* p = x + (size_t)vr * D + ks * 32 + quad * 8;
            float4 lo = *(const float4*)p;
            float4 hi = *(const float4*)(p + 4);
            bf16x8 f;
            f[0] = f2bf(lo.x); f[1] = f2bf(lo.y); f[2] = f2bf(lo.z); f[3] = f2bf(lo.w);
            f[4] = f2bf(hi.x); f[5] = f2bf(hi.y); f[6] = f2bf(hi.z); f[7] = f2bf(hi.w);
            a[ks] = f;
        }

#pragma unroll
        for (int nb = 0; nb < 4; ++nb) {
            f32x4 acc = {0.f, 0.f, 0.f, 0.f};
            acc = __builtin_amdgcn_mfma_f32_16x16x32_bf16(a[0], w1f[0][nb], acc, 0, 0, 0);
            acc = __builtin_amdgcn_mfma_f32_16x16x32_bf16(a[1], w1f[1][nb], acc, 0, 0, 0);
#pragma unroll
            for (int r = 0; r < 4; ++r) {
                float hv = fmaxf(acc[r] + b1v[nb], 0.f);
                Hw[(quad * 4 + r) * 72 + nb * 16 + mr] = __float2bfloat16(hv);
            }
        }

        bf16x8 h[2];
#pragma unroll
        for (int ks = 0; ks < 2; ++ks)
            h[ks] = *(const bf16x8*)&Hw[mr * 72 + ks * 32 + quad * 8];

#pragma unroll
        for (int nb = 0; nb < 4; ++nb) {
            f32x4 acc = {0.f, 0.f, 0.f, 0.f};
            acc = __builtin_amdgcn_mfma_f32_16x16x32_bf16(h[0], w2f[0][nb], acc, 0, 0, 0);
            acc = __builtin_amdgcn_mfma_f32_16x16x32_bf16(h[1], w2f[1][nb], acc, 0, 0, 0);
#pragma unroll
            for (int r = 0; r < 4; ++r) {
                int vrow = v0 + quad * 4 + r;
                if (vrow < n_nodes)
                    m[(size_t)vrow * D + nb * 16 + mr] = acc[r] + b2v[nb];
            }
        }
    }
}

// ---------------------------------------------------------------------------
// CSR build: histogram + 3-phase scan (unchanged), then binned 2-phase fill.
// ---------------------------------------------------------------------------
__global__ __launch_bounds__(256) void hist_kernel(
    const int* __restrict__ col, int* __restrict__ deg, int n_edges)
{
    int e = blockIdx.x * blockDim.x + threadIdx.x;
    if (e < n_edges) atomicAdd(&deg[col[e]], 1);
}

__global__ __launch_bounds__(256) void scan_partial_kernel(
    const int* __restrict__ deg, int* __restrict__ bsum, int n)
{
    __shared__ int ws[4];
    const int g = blockIdx.x * 256 + threadIdx.x;
    int v = (g < n) ? deg[g] : 0;
#pragma unroll
    for (int off = 32; off > 0; off >>= 1)
        v += __shfl_down(v, off, 64);
    if ((threadIdx.x & 63) == 0) ws[threadIdx.x >> 6] = v;
    __syncthreads();
    if (threadIdx.x == 0)
        bsum[blockIdx.x] = ws[0] + ws[1] + ws[2] + ws[3];
}

__global__ __launch_bounds__(512) void scan_tops_kernel(
    const int* __restrict__ bsum, int* __restrict__ bscan, int nparts)
{
    __shared__ int tmp[512];
    const int t = threadIdx.x;
    int v = (t < nparts) ? bsum[t] : 0;
    tmp[t] = v;
    __syncthreads();
    for (int off = 1; off < 512; off <<= 1) {
        int u = (t >= off) ? tmp[t - off] : 0;
        __syncthreads();
        tmp[t] += u;
        __syncthreads();
    }
    if (t < nparts) bscan[t] = tmp[t] - v;   // exclusive
}

__global__ __launch_bounds__(256) void scan_apply_kernel(
    const int* __restrict__ deg, const int* __restrict__ bscan,
    int* __restrict__ offs, int n)
{
    __shared__ int tmp[256];
    const int t = threadIdx.x;
    const int g = blockIdx.x * 256 + t;
    int v = (g < n) ? deg[g] : 0;
    tmp[t] = v;
    __syncthreads();
    for (int off = 1; off < 256; off <<= 1) {
        int u = (t >= off) ? tmp[t - off] : 0;
        __syncthreads();
        tmp[t] += u;
        __syncthreads();
    }
    if (g < n)
        offs[g] = bscan[blockIdx.x] + tmp[t] - v;  // exclusive prefix
}

// gcur[b] = start offset of coarse bucket b in the edge-sorted array.
__global__ __launch_bounds__(64) void gcur_init_kernel(
    const int* __restrict__ offs, int* __restrict__ gcur, int nbuckets)
{
    int t = blockIdx.x * blockDim.x + threadIdx.x;
    if (t < nbuckets) gcur[t] = offs[t << BSHIFT];
}

// Pass B: bin edges by coarse destination bucket into tmp (packed u32).
// Per-block per-bucket ranges are contiguous -> writes merge in L2.
__global__ __launch_bounds__(256) void bin_kernel(
    const int* __restrict__ row, const int* __restrict__ col,
    int* __restrict__ gcur, unsigned int* __restrict__ tmp,
    int n_edges, int nbuckets, int chunk)
{
    __shared__ int hist[MAXK], base[MAXK], lcur[MAXK];
    const int t = threadIdx.x;
    const int e0 = blockIdx.x * chunk;
    const int e1 = min(e0 + chunk, n_edges);

    for (int i = t; i < nbuckets; i += 256) hist[i] = 0;
    __syncthreads();
    for (int e = e0 + t; e < e1; e += 256)
        atomicAdd(&hist[col[e] >> BSHIFT], 1);
    __syncthreads();
    for (int i = t; i < nbuckets; i += 256) {
        base[i] = atomicAdd(&gcur[i], hist[i]);
        lcur[i] = 0;
    }
    __syncthreads();
    for (int e = e0 + t; e < e1; e += 256) {
        int c = col[e];
        int b = c >> BSHIFT;
        int loc = atomicAdd(&lcur[b], 1);
        unsigned int val = ((unsigned int)(c & (BW - 1)) << 17)
                         | (unsigned int)row[e];
        tmp[base[b] + loc] = val;
    }
}

// Pass C: one block per bucket; per-node cursors in LDS; scatter writes land
// in an ~80 KB L2-resident region -> merged writeback.
__global__ __launch_bounds__(256) void fillc_kernel(
    const unsigned int* __restrict__ tmp, const int* __restrict__ offs,
    int* __restrict__ srcs, int n_nodes, int n_edges)
{
    __shared__ int lcur[BW];
    const int t = threadIdx.x;
    const int vbase = blockIdx.x << BSHIFT;
    const int nloc = min(BW, n_nodes - vbase);

    for (int j = t; j < nloc; j += 256) lcur[j] = offs[vbase + j];
    __syncthreads();

    const int start = offs[vbase];
    const int end = (vbase + BW >= n_nodes) ? n_edges : offs[vbase + BW];
    for (int i = start + t; i < end; i += 256) {
        unsigned int val = tmp[i];
        int cl = (int)(val >> 17);
        int r  = (int)(val & 0x1FFFFu);
        int pos = atomicAdd(&lcur[cl], 1);
        srcs[pos] = r;
    }
}

// ---------------------------------------------------------------------------
// K2: atomic-free gather.  agg[v] = sum over incoming edges of m[src].
// ---------------------------------------------------------------------------
__global__ __launch_bounds__(256) void gather_kernel(
    const int* __restrict__ offs, const int* __restrict__ deg,
    const int* __restrict__ srcs, const float* __restrict__ m,
    float* __restrict__ agg, int n_nodes)
{
    const int lane = threadIdx.x & 63;
    const int v    = (blockIdx.x * blockDim.x + threadIdx.x) >> 6;
    if (v >= n_nodes) return;

    const int start = offs[v];
    const int end   = start + deg[v];

    float s = 0.0f;
    for (int cs = start; cs < end; cs += 64) {
        const int cnt = min(64, end - cs);
        int rl = 0;
        if (lane < cnt) rl = srcs[cs + lane];

        int j = 0;
        for (; j + 4 <= cnt; j += 4) {
            int r0 = __builtin_amdgcn_readlane(rl, j + 0);
            int r1 = __builtin_amdgcn_readlane(rl, j + 1);
            int r2 = __builtin_amdgcn_readlane(rl, j + 2);
            int r3 = __builtin_amdgcn_readlane(rl, j + 3);
            float v0 = m[(size_t)r0 * D + lane];
            float v1 = m[(size_t)r1 * D + lane];
            float v2 = m[(size_t)r2 * D + lane];
            float v3 = m[(size_t)r3 * D + lane];
            s += v0; s += v1; s += v2; s += v3;
        }
        for (; j < cnt; ++j) {
            int r = __builtin_amdgcn_readlane(rl, j);
            s += m[(size_t)r * D + lane];
        }
    }
    agg[(size_t)v * D + lane] = s;
}

// ---------------------------------------------------------------------------
// Fallback scatter (only if ws too small / shape out of range): fp32 atomics.
// ---------------------------------------------------------------------------
__global__ __launch_bounds__(256) void scatter_kernel(
    const int* __restrict__ row, const int* __restrict__ col,
    const float* __restrict__ m, float* __restrict__ agg, int n_edges)
{
    const int lane = threadIdx.x & 63;
    const int wid  = (blockIdx.x * blockDim.x + threadIdx.x) >> 6;
    const int base = wid * 64;
    if (base >= n_edges) return;
    const int cnt = min(64, n_edges - base);

    int my_r = 0, my_c = 0;
    if (lane < cnt) { my_r = row[base + lane]; my_c = col[base + lane]; }

    for (int j = 0; j < cnt; ++j) {
        int r = __builtin_amdgcn_readlane(my_r, j);
        int c = __builtin_amdgcn_readlane(my_c, j);
        float v = m[(size_t)r * D + lane];
        atomicAdd(&agg[(size_t)c * D + lane], v);
    }
}

// ---------------------------------------------------------------------------
// K3: output MLP via MFMA.  out[v] = relu([x[v],agg[v]]@OW1 + ob1)@OW2 + ob2
// ---------------------------------------------------------------------------
__global__ __launch_bounds__(256) void out_kernel(
    const float* __restrict__ x, const float* __restrict__ agg,
    const float* __restrict__ w1, const float* __restrict__ b1,
    const float* __restrict__ w2, const float* __restrict__ b2,
    float* __restrict__ out, int n_nodes)
{
    __shared__ __align__(16) __hip_bfloat16 sH[4][16 * 72];

    const int lane = threadIdx.x & 63;
    const int wslot = threadIdx.x >> 6;
    const int mr   = lane & 15;
    const int quad = lane >> 4;

    bf16x8 w1f[4][4], w2f[2][4];
    float  b1v[4], b2v[4];
#pragma unroll
    for (int ks = 0; ks < 4; ++ks)
#pragma unroll
        for (int nb = 0; nb < 4; ++nb) {
            bf16x8 f;
#pragma unroll
            for (int j = 0; j < 8; ++j) {
                int k = ks * 32 + quad * 8 + j;
                f[j] = f2bf(w1[k * D + nb * 16 + mr]);
            }
            w1f[ks][nb] = f;
        }
#pragma unroll
    for (int ks = 0; ks < 2; ++ks)
#pragma unroll
        for (int nb = 0; nb < 4; ++nb) {
            bf16x8 f;
#pragma unroll
            for (int j = 0; j < 8; ++j) {
                int k = ks * 32 + quad * 8 + j;
                f[j] = f2bf(w2[k * D + nb * 16 + mr]);
            }
            w2f[ks][nb] = f;
        }
#pragma unroll
    for (int nb = 0; nb < 4; ++nb) {
        b1v[nb] = b1[nb * 16 + mr];
        b2v[nb] = b2[nb * 16 + mr];
    }

    __hip_bfloat16* Hw = sH[wslot];
    const int wid    = (blockIdx.x * blockDim.x + threadIdx.x) >> 6;
    const int nwaves = (gridDim.x * blockDim.x) >> 6;
    const int ntiles = (n_nodes + 15) >> 4;

    for (int t = wid; t < ntiles; t += nwaves) {
        const int v0 = t * 16;
        int vr = v0 + mr;
        if (vr >= n_nodes) vr = n_nodes - 1;

        bf16x8 a[4];
#pragma unroll
        for (int ks = 0; ks < 4; ++ks) {
            const float* src = (ks < 2) ? (x + (size_t)vr * D + ks * 32)
                                        : (agg + (size_t)vr * D + (ks - 2) * 32);
            const float* p = src + quad * 8;
            float4 lo = *(const float4*)p;
            float4 hi = *(const float4*)(p + 4);
            bf16x8 f;
            f[0] = f2bf(lo.x); f[1] = f2bf(lo.y); f[2] = f2bf(lo.z); f[3] = f2bf(lo.w);
            f[4] = f2bf(hi.x); f[5] = f2bf(hi.y); f[6] = f2bf(hi.z); f[7] = f2bf(hi.w);
            a[ks] = f;
        }

#pragma unroll
        for (int nb = 0; nb < 4; ++nb) {
            f32x4 acc = {0.f, 0.f, 0.f, 0.f};
#pragma unroll
            for (int ks = 0; ks < 4; ++ks)
                acc = __builtin_amdgcn_mfma_f32_16x16x32_bf16(a[ks], w1f[ks][nb], acc, 0, 0, 0);
#pragma unroll
            for (int r = 0; r < 4; ++r) {
                float hv = fmaxf(acc[r] + b1v[nb], 0.f);
                Hw[(quad * 4 + r) * 72 + nb * 16 + mr] = __float2bfloat16(hv);
            }
        }

        bf16x8 h[2];
#pragma unroll
        for (int ks = 0; ks < 2; ++ks)
            h[ks] = *(const bf16x8*)&Hw[mr * 72 + ks * 32 + quad * 8];

#pragma unroll
        for (int nb = 0; nb < 4; ++nb) {
            f32x4 acc = {0.f, 0.f, 0.f, 0.f};
            acc = __builtin_amdgcn_mfma_f32_16x16x32_bf16(h[0], w2f[0][nb], acc, 0, 0, 0);
            acc = __builtin_amdgcn_mfma_f32_16x16x32_bf16(h[1], w2f[1][nb], acc, 0, 0, 0);
#pragma unroll
            for (int r = 0; r < 4; ++r) {
                int vrow = v0 + quad * 4 + r;
                if (vrow < n_nodes)
                    out[(size_t)vrow * D + nb * 16 + mr] = acc[r] + b2v[nb];
            }
        }
    }
}

// ---------------------------------------------------------------------------
extern "C" void kernel_launch(void* const* d_in, const int* in_sizes, int n_in,
                              void* d_out, int out_size, void* d_ws, size_t ws_size,
                              hipStream_t stream) {
    const float* x   = (const float*)d_in[0];
    const int*   ei  = (const int*)d_in[1];
    // d_in[2] = batch (unused)
    const float* mw1 = (const float*)d_in[3];
    const float* mb1 = (const float*)d_in[4];
    const float* mw2 = (const float*)d_in[5];
    const float* mb2 = (const float*)d_in[6];
    const float* ow1 = (const float*)d_in[7];
    const float* ob1 = (const float*)d_in[8];
    const float* ow2 = (const float*)d_in[9];
    const float* ob2 = (const float*)d_in[10];

    const int n_nodes = in_sizes[0] / D;        // 100000
    const int n_edges = in_sizes[1] / 2;        // 1000000
    const int* row = ei;                        // edge_index[0]
    const int* col = ei + n_edges;              // edge_index[1]

    const int nparts   = (n_nodes + 255) / 256;       // 391 (<= 512)
    const int nbuckets = (n_nodes + BW - 1) >> BSHIFT; // 49 (<= MAXK)

    // ws layout
    float* m   = (float*)d_ws;                       // [n_nodes*64] f32
    float* agg = m + (size_t)n_nodes * D;            // [n_nodes*64] f32
    int* deg   = (int*)(agg + (size_t)n_nodes * D);  // [n_nodes]
    int* offs  = deg + n_nodes;                      // [n_nodes]
    int* srcs  = offs + n_nodes;                     // [n_edges]
    int* bsum  = srcs + n_edges;                     // [nparts]
    int* bscan = bsum + nparts;                      // [nparts]
    int* gcur  = bscan + nparts;                     // [nbuckets]
    unsigned int* tmp = (unsigned int*)agg;          // aliases agg (safe: read
                                                     // before gather rewrites agg)
    const size_t need_csr = (size_t)n_nodes * D * 8 + (size_t)n_nodes * 8
                          + (size_t)n_edges * 4
                          + (size_t)nparts * 8 + (size_t)nbuckets * 4;

    const int ntiles = (n_nodes + 15) / 16;
    const int nblk   = (ntiles + 3) / 4;

    msg_kernel<<<nblk, 256, 0, stream>>>(x, mw1, mb1, mw2, mb2, m, n_nodes);

    const bool shape_ok = (n_nodes <= (MAXK << BSHIFT)) && (n_nodes < (1 << 17))
                       && (nparts <= 512);

    if (ws_size >= need_csr && shape_ok) {
        hipMemsetAsync(deg, 0, (size_t)n_nodes * sizeof(int), stream);
        hist_kernel<<<(n_edges + 255) / 256, 256, 0, stream>>>(col, deg, n_edges);
        scan_partial_kernel<<<nparts, 256, 0, stream>>>(deg, bsum, n_nodes);
        scan_tops_kernel<<<1, 512, 0, stream>>>(bsum, bscan, nparts);
        scan_apply_kernel<<<nparts, 256, 0, stream>>>(deg, bscan, offs, n_nodes);
        gcur_init_kernel<<<(nbuckets + 63) / 64, 64, 0, stream>>>(offs, gcur, nbuckets);

        const int nbbin = 256;
        const int chunk = (n_edges + nbbin - 1) / nbbin;
        bin_kernel<<<nbbin, 256, 0, stream>>>(row, col, gcur, tmp,
                                              n_edges, nbuckets, chunk);
        fillc_kernel<<<nbuckets, 256, 0, stream>>>(tmp, offs, srcs,
                                                   n_nodes, n_edges);
        gather_kernel<<<(n_nodes + 3) / 4, 256, 0, stream>>>(offs, deg, srcs,
                                                             m, agg, n_nodes);
    } else {
        hipMemsetAsync(agg, 0, (size_t)n_nodes * D * sizeof(float), stream);
        const int nwaves_s = (n_edges + 63) / 64;
        scatter_kernel<<<(nwaves_s + 3) / 4, 256, 0, stream>>>(row, col, m, agg, n_edges);
    }

    out_kernel<<<nblk, 256, 0, stream>>>(x, agg, ow1, ob1, ow2, ob2,
                                         (float*)d_out, n_nodes);
}